// Round 3
// baseline (213.171 us; speedup 1.0000x reference)
//
#include <hip/hip_runtime.h>

// DMoE (PLE/CGC) fused kernel for MI355X (gfx950).
// B=32768, D_IN=256, H=128, N_TASK=2, N_EXP=4, N_SHARE=4.
//
// R10: TLP round. R7 (76.7us, best) and R9 (93.5us) both ran ONE
// barrier-synced 8-wave stream per CU (~160-190 live regs -> 2-3 waves/SIMD,
// 512-thr blocks quantize to 1 block/CU) -> ~85% stall, no pipe >25% busy.
// R10 keeps R7's proven micro-structure (16x16x32 fragments, 272B padded
// rows, reg-staged deposits, __syncthreads loop, per-XCD task affinity)
// but re-tiles for 4 independent blocks/CU:
//  - 256-thr blocks (4 waves), block = 64 rows x 64 h x one task.
//  - wave = 32r x 32h (mt2 x nt2): A[2][8]=64 + acc16 + tw16 + stage17
//    + addr ~ 127 regs -> 4 waves/SIMD at __launch_bounds__(256,4).
//  - blocks stage contiguous 17KB h-half-units, dbuf: LDS 39KB -> 4 blk/CU.
//  - x loads NOT nontemporal (x-tile now shared by 4 blocks via L3).
//  - setprio(1) around MFMA (4 out-of-phase blocks/CU -> real arbitration).
// prep_kernel and weight-image layout are verbatim R7 (proven).

typedef __attribute__((ext_vector_type(8))) short short8;   // 8 x bf16
typedef __attribute__((ext_vector_type(4))) float float4v;  // MFMA C/D

#define ROW_US     136        // 128 data + 8 pad (bf16)
#define ROW_B      272
#define UNIT_US    17408      // 128 rows x 136 (half-expert: 128h x 128k)
#define UNIT_B     34816
#define HUNIT_B    17408      // h-half of a unit (64 rows x 272 B)
#define WAVE_B     4352       // HUNIT_B / 4 waves
#define WGT_OFF_US 417792     // 24 * 17408
#define COPY_US    421888     // + 16*256 gate ushorts
#define COPY_B     843776

__device__ __forceinline__ unsigned short f2bf(float f) {
  unsigned u = __builtin_bit_cast(unsigned, f);
  u += 0x7FFFu + ((u >> 16) & 1u);   // round-to-nearest-even
  return (unsigned short)(u >> 16);
}

__device__ __forceinline__ int slot2e(int sr, int t) {
  return (sr < 4) ? sr : 4 + t * 4 + (sr - 4);
}

// ---------------------------------------------------------------------------
// Prep: WT[c][e][kh] units (128h x 136k bf16) + WgT[16][256] per copy.
// (verbatim R7 - proven)
__global__ __launch_bounds__(256)
void prep_kernel(const float* __restrict__ Ws,
                 const float* __restrict__ Wt,
                 const float* __restrict__ Wg,
                 unsigned short* __restrict__ WT, int NC) {
  int bid = blockIdx.x;
  int tid = threadIdx.x;
  if (bid < 96) {
    __shared__ float tile[64][65];
    int e  = bid >> 3;
    int kt = (bid >> 1) & 3;   // 64-wide k tile; kh = kt>>1
    int ht = bid & 1;          // h half
    const float* src = (e < 4) ? Ws + ((size_t)e << 15)
                               : Wt + ((size_t)(e - 4) << 15);
    int m = tid & 15, n = tid >> 4;
    #pragma unroll
    for (int i = 0; i < 4; ++i) {   // coalesced read of src[k][h]
      int kl = i * 16 + n;
      float4 v = *(const float4*)&src[(size_t)(kt * 64 + kl) * 128 + ht * 64 + m * 4];
      tile[kl][m * 4 + 0] = v.x;
      tile[kl][m * 4 + 1] = v.y;
      tile[kl][m * 4 + 2] = v.z;
      tile[kl][m * 4 + 3] = v.w;
    }
    __syncthreads();
    #pragma unroll
    for (int i = 0; i < 4; ++i) {
      int hl = i * 16 + n;
      ushort4 o;
      o.x = f2bf(tile[m * 4 + 0][hl]);
      o.y = f2bf(tile[m * 4 + 1][hl]);
      o.z = f2bf(tile[m * 4 + 2][hl]);
      o.w = f2bf(tile[m * 4 + 3][hl]);
      size_t rowbase = (size_t)(e * 2 + (kt >> 1)) * UNIT_US
                     + (size_t)(ht * 64 + hl) * ROW_US + (kt & 1) * 64;
      for (int c = 0; c < NC; ++c) {
        *(ushort4*)&WT[(size_t)c * COPY_US + rowbase + m * 4] = o;
        if ((kt & 1) == 1 && m < 2) {           // zero row pad [128,136)
          ushort4 z = {0, 0, 0, 0};
          *(ushort4*)&WT[(size_t)c * COPY_US + rowbase + 64 + m * 4] = z;
        }
      }
    }
  } else {
    // gate weights WgT[n][256], n = t*8+g
    #pragma unroll
    for (int it = 0; it < 16; ++it) {
      int j = it * 256 + tid;
      int n = j >> 8, k = j & 255;
      int t = n >> 3, g = n & 7;
      unsigned short v = f2bf(Wg[(size_t)(t * 256 + k) * 8 + g]);
      for (int c = 0; c < NC; ++c)
        WT[(size_t)c * COPY_US + WGT_OFF_US + j] = v;
    }
  }
}

// ---------------------------------------------------------------------------
__global__ __launch_bounds__(256, 4)
void dmoe_main(const float* __restrict__ x,
               const unsigned short* __restrict__ WT,
               const float* __restrict__ b_share,
               const float* __restrict__ b_task,
               const float* __restrict__ b_gate,
               float* __restrict__ out, int NC) {
  __shared__ unsigned short Bs0[HUNIT_B / 2];   // 17408 B (64 h-rows)
  __shared__ unsigned short Bs1[HUNIT_B / 2];   // 17408 B
  __shared__ float gatesL[8 * 68];              // [gate-col][row(64)+pad]
  __shared__ float biasLds[8 * 64];             // slot-indexed, block h-range

  const int tid  = threadIdx.x;
  const int lane = tid & 63;
  const int w    = tid >> 6;    // wave 0..3
  const int col  = lane & 15;
  const int quad = lane >> 4;
  const int mg   = w >> 1;      // rows [mg*32, mg*32+32)
  const int ng   = w & 1;       // h    [ng*32, ng*32+32) within block h-half
  const int blk  = blockIdx.x;
  const int t    = blk & 1;     // task (== XCD parity: one task per XCD)
  const int hh   = (blk >> 1) & 1;   // h half of the units
  const int rt   = blk >> 2;    // row tile (64 rows)
  const int rot  = (blk >> 3) & 7;

  const char* WTc = (const char*)WT + (size_t)((blk >> 3) % NC) * COPY_B;

  // ---- reg staging of this wave's 4352-B chunk of one h-half-unit ----
  uint4 p0, p1, p2, p3; unsigned p4;
  auto stageIssue = [&](int un) {
    const char* g = WTc + (size_t)un * UNIT_B + hh * HUNIT_B + w * WAVE_B;
    p0 = *(const uint4*)(g + lane * 16);
    p1 = *(const uint4*)(g + 1024 + lane * 16);
    p2 = *(const uint4*)(g + 2048 + lane * 16);
    p3 = *(const uint4*)(g + 3072 + lane * 16);
    p4 = *(const unsigned*)(g + 4096 + lane * 4);
  };
  auto deposit = [&](unsigned short* dst) {
    char* l = (char*)dst + w * WAVE_B;
    *(uint4*)(l + lane * 16)        = p0;
    *(uint4*)(l + 1024 + lane * 16) = p1;
    *(uint4*)(l + 2048 + lane * 16) = p2;
    *(uint4*)(l + 3072 + lane * 16) = p3;
    *(unsigned*)(l + 4096 + lane * 4) = p4;
  };

  // ---- issue first unit's loads first (longest latency) ----
  const int e0 = slot2e(rot, t);
  stageIssue(e0 * 2);

  // ---- A-fragments: 2 m-tiles x 8 k-steps resident (regular x loads) ----
  short8 A[2][8];
  {
    const float* xb = x + ((size_t)rt * 64 + mg * 32 + col) * 256 + quad * 8;
    #pragma unroll
    for (int mt = 0; mt < 2; ++mt) {
      const float* xr = xb + (size_t)mt * 16 * 256;
      #pragma unroll
      for (int k = 0; k < 8; ++k) {
        float4v u = *(const float4v*)(xr + k * 32);
        float4v v = *(const float4v*)(xr + k * 32 + 4);
        short8 fr;
        fr[0] = (short)f2bf(u[0]); fr[1] = (short)f2bf(u[1]);
        fr[2] = (short)f2bf(u[2]); fr[3] = (short)f2bf(u[3]);
        fr[4] = (short)f2bf(v[0]); fr[5] = (short)f2bf(v[1]);
        fr[6] = (short)f2bf(v[2]); fr[7] = (short)f2bf(v[3]);
        A[mt][k] = fr;
      }
    }
  }

  // ---- deposit first unit (frees p-regs before the gate phase) ----
  deposit(Bs0);

  // ---- biases -> LDS (slot-indexed; only this block's 64-h range) ----
  for (int i = tid; i < 512; i += 256) {
    int sr = i >> 6, hl = i & 63, h = hh * 64 + hl;
    biasLds[i] = (sr < 4) ? b_share[sr * 128 + h]
                          : b_task[(size_t)(t * 4 + (sr - 4)) * 128 + h];
  }

  // ---- gates: this task's 8 logit cols (cols 8..15 duplicate 0..7) ----
  {
    const unsigned short* WgT = (const unsigned short*)(WTc + WGT_OFF_US * 2);
    const int gr = col & 7;
    const unsigned short* bp = WgT + (size_t)(t * 8 + gr) * 256 + quad * 8;
    float bg = b_gate[t * 8 + gr];
    float4v ag[2] = {{0.f,0.f,0.f,0.f},{0.f,0.f,0.f,0.f}};
    #pragma unroll
    for (int kb = 0; kb < 2; ++kb) {           // 2 k-halves: caps reg peak
      short8 Bg[4];
      #pragma unroll
      for (int j = 0; j < 4; ++j) Bg[j] = *(const short8*)(bp + (kb * 4 + j) * 32);
      #pragma unroll
      for (int j = 0; j < 4; ++j) {
        ag[0] = __builtin_amdgcn_mfma_f32_16x16x32_bf16(A[0][kb * 4 + j], Bg[j], ag[0], 0, 0, 0);
        ag[1] = __builtin_amdgcn_mfma_f32_16x16x32_bf16(A[1][kb * 4 + j], Bg[j], ag[1], 0, 0, 0);
      }
    }
    #pragma unroll
    for (int mt = 0; mt < 2; ++mt) {
      #pragma unroll
      for (int r = 0; r < 4; ++r) {
        float vlog = ag[mt][r] + bg;
        float m = vlog;                      // softmax over 8 cols
        m = fmaxf(m, __shfl_xor(m, 1));
        m = fmaxf(m, __shfl_xor(m, 2));
        m = fmaxf(m, __shfl_xor(m, 4));
        float p = __expf(vlog - m);
        float s = p;
        s += __shfl_xor(s, 1);
        s += __shfl_xor(s, 2);
        s += __shfl_xor(s, 4);
        if (ng == 0 && col < 8)
          gatesL[col * 68 + mg * 32 + mt * 16 + quad * 4 + r] = p / s;
      }
    }
  }
  __syncthreads();

  // ---- accumulators (task-local) ----
  float tw[2][2][4];   // [mt][nt][r]
  #pragma unroll
  for (int mt = 0; mt < 2; ++mt)
    #pragma unroll
    for (int nt = 0; nt < 2; ++nt)
      #pragma unroll
      for (int r = 0; r < 4; ++r)
        tw[mt][nt][r] = 0.f;

  const int hb = ng * 32;
  float4v acc[2][2];

  // ---- slot loop: 8 experts x 2 k-halves; buffer parity = kh ----
  #pragma unroll 1
  for (int s = 0; s < 8; ++s) {
    const int sr  = (s + rot) & 7;
    const int e   = slot2e(sr, t);
    const int e2  = slot2e((s + 1 + rot) & 7, t);
    #pragma unroll
    for (int kh = 0; kh < 2; ++kh) {
      const bool doStage = !(s == 7 && kh == 1);
      if (doStage) stageIssue(kh == 0 ? e * 2 + 1 : e2 * 2);
      if (kh == 0) {
        #pragma unroll
        for (int mt = 0; mt < 2; ++mt)
          #pragma unroll
          for (int nt = 0; nt < 2; ++nt)
            acc[mt][nt] = (float4v){0.f, 0.f, 0.f, 0.f};
      }
      // compute this half-unit from Bs[kh]
      {
        const char* Bb = (const char*)(kh ? Bs1 : Bs0);
        __builtin_amdgcn_s_setprio(1);
        #pragma unroll
        for (int kk = 0; kk < 4; ++kk) {
          #pragma unroll
          for (int nt = 0; nt < 2; ++nt) {
            short8 bfr = *(const short8*)(Bb + (hb + nt * 16 + col) * ROW_B
                                          + kk * 64 + quad * 16);
            acc[0][nt] = __builtin_amdgcn_mfma_f32_16x16x32_bf16(
                A[0][kh * 4 + kk], bfr, acc[0][nt], 0, 0, 0);
            acc[1][nt] = __builtin_amdgcn_mfma_f32_16x16x32_bf16(
                A[1][kh * 4 + kk], bfr, acc[1][nt], 0, 0, 0);
          }
        }
        __builtin_amdgcn_s_setprio(0);
      }
      // deposit prefetched unit into the other buffer
      if (doStage) deposit(kh ? Bs0 : Bs1);
      // epilogue after second half
      if (kh == 1) {
        #pragma unroll
        for (int mt = 0; mt < 2; ++mt) {
          int rb = mg * 32 + mt * 16 + quad * 4;
          float4 g = *(const float4*)&gatesL[sr * 68 + rb];
          #pragma unroll
          for (int nt = 0; nt < 2; ++nt) {
            float bias = biasLds[sr * 64 + hb + nt * 16 + col];
            #pragma unroll
            for (int r = 0; r < 4; ++r) {
              float v = fmaxf(acc[mt][nt][r] + bias, 0.f);
              tw[mt][nt][r] += ((const float*)&g)[r] * v;
            }
          }
        }
      }
      __syncthreads();
    }
  }

  // ---- write towers (nontemporal): out[t][row][h] ----
  #pragma unroll
  for (int mt = 0; mt < 2; ++mt)
    #pragma unroll
    for (int r = 0; r < 4; ++r) {
      size_t row = (size_t)rt * 64 + mg * 32 + mt * 16 + quad * 4 + r;
      float* op = out + ((size_t)t << 22) + row * 128 + hh * 64 + hb;
      #pragma unroll
      for (int nt = 0; nt < 2; ++nt)
        __builtin_nontemporal_store(tw[mt][nt][r], op + nt * 16 + col);
    }
}

// ---------------------------------------------------------------------------
extern "C" void kernel_launch(void* const* d_in, const int* in_sizes, int n_in,
                              void* d_out, int out_size, void* d_ws, size_t ws_size,
                              hipStream_t stream) {
  const float* x       = (const float*)d_in[0];
  const float* W_share = (const float*)d_in[1];
  const float* b_share = (const float*)d_in[2];
  const float* W_task  = (const float*)d_in[3];
  const float* b_task  = (const float*)d_in[4];
  const float* W_gate  = (const float*)d_in[5];
  const float* b_gate  = (const float*)d_in[6];
  float* out = (float*)d_out;
  unsigned short* WT = (unsigned short*)d_ws;

  int NC = (int)(ws_size / (size_t)COPY_B);
  if (NC < 1) NC = 1;
  if (NC > 2) NC = 2;

  prep_kernel<<<97, 256, 0, stream>>>(W_share, W_task, W_gate, WT, NC);
  dmoe_main<<<2048, 256, 0, stream>>>(x, WT, b_share, b_task, b_gate, out, NC);
}

// Round 4
// 170.723 us; speedup vs baseline: 1.2486x; 1.2486x over previous
//
#include <hip/hip_runtime.h>

// DMoE (PLE/CGC) fused kernel for MI355X (gfx950).
// B=32768, D_IN=256, H=128, N_TASK=2, N_EXP=4, N_SHARE=4.
//
// R11 = R10 geometry (4-wave 256-thr blocks, 64r x 64h x 1 task, h-half-unit
// double-buffer, reg-staged deposits, __syncthreads loop) with the register
// fix the R10 counters demanded:
//  - R10's __launch_bounds__(256,4) made the allocator emit VGPR_Count=64
//    against a ~130-reg live set -> 190 MB scratch round-trip (WRITE 143 MB),
//    spill-BW-bound at 137us.
//  - A[2][8] now pinned into AGPRs (asm "+a", proven spill-free in R9);
//    arch-VGPR live set ~75.
//  - __launch_bounds__(256,3): 170-reg unified budget >= 64 AGPR + ~100 VGPR,
//    3 blocks/CU (3 independent barrier groups; R7 had 1). LDS 118 KB/CU.
// prep_kernel and weight-image layout verbatim R7 (proven).

typedef __attribute__((ext_vector_type(8))) short short8;   // 8 x bf16
typedef __attribute__((ext_vector_type(4))) float float4v;  // MFMA C/D

#define ROW_US     136        // 128 data + 8 pad (bf16)
#define ROW_B      272
#define UNIT_US    17408      // 128 rows x 136 (half-expert: 128h x 128k)
#define UNIT_B     34816
#define HUNIT_B    17408      // h-half of a unit (64 rows x 272 B)
#define WAVE_B     4352       // HUNIT_B / 4 waves
#define WGT_OFF_US 417792     // 24 * 17408
#define COPY_US    421888     // + 16*256 gate ushorts
#define COPY_B     843776

__device__ __forceinline__ unsigned short f2bf(float f) {
  unsigned u = __builtin_bit_cast(unsigned, f);
  u += 0x7FFFu + ((u >> 16) & 1u);   // round-to-nearest-even
  return (unsigned short)(u >> 16);
}

__device__ __forceinline__ int slot2e(int sr, int t) {
  return (sr < 4) ? sr : 4 + t * 4 + (sr - 4);
}

// ---------------------------------------------------------------------------
// Prep: WT[c][e][kh] units (128h x 136k bf16) + WgT[16][256] per copy.
// (verbatim R7 - proven)
__global__ __launch_bounds__(256)
void prep_kernel(const float* __restrict__ Ws,
                 const float* __restrict__ Wt,
                 const float* __restrict__ Wg,
                 unsigned short* __restrict__ WT, int NC) {
  int bid = blockIdx.x;
  int tid = threadIdx.x;
  if (bid < 96) {
    __shared__ float tile[64][65];
    int e  = bid >> 3;
    int kt = (bid >> 1) & 3;   // 64-wide k tile; kh = kt>>1
    int ht = bid & 1;          // h half
    const float* src = (e < 4) ? Ws + ((size_t)e << 15)
                               : Wt + ((size_t)(e - 4) << 15);
    int m = tid & 15, n = tid >> 4;
    #pragma unroll
    for (int i = 0; i < 4; ++i) {   // coalesced read of src[k][h]
      int kl = i * 16 + n;
      float4 v = *(const float4*)&src[(size_t)(kt * 64 + kl) * 128 + ht * 64 + m * 4];
      tile[kl][m * 4 + 0] = v.x;
      tile[kl][m * 4 + 1] = v.y;
      tile[kl][m * 4 + 2] = v.z;
      tile[kl][m * 4 + 3] = v.w;
    }
    __syncthreads();
    #pragma unroll
    for (int i = 0; i < 4; ++i) {
      int hl = i * 16 + n;
      ushort4 o;
      o.x = f2bf(tile[m * 4 + 0][hl]);
      o.y = f2bf(tile[m * 4 + 1][hl]);
      o.z = f2bf(tile[m * 4 + 2][hl]);
      o.w = f2bf(tile[m * 4 + 3][hl]);
      size_t rowbase = (size_t)(e * 2 + (kt >> 1)) * UNIT_US
                     + (size_t)(ht * 64 + hl) * ROW_US + (kt & 1) * 64;
      for (int c = 0; c < NC; ++c) {
        *(ushort4*)&WT[(size_t)c * COPY_US + rowbase + m * 4] = o;
        if ((kt & 1) == 1 && m < 2) {           // zero row pad [128,136)
          ushort4 z = {0, 0, 0, 0};
          *(ushort4*)&WT[(size_t)c * COPY_US + rowbase + 64 + m * 4] = z;
        }
      }
    }
  } else {
    // gate weights WgT[n][256], n = t*8+g
    #pragma unroll
    for (int it = 0; it < 16; ++it) {
      int j = it * 256 + tid;
      int n = j >> 8, k = j & 255;
      int t = n >> 3, g = n & 7;
      unsigned short v = f2bf(Wg[(size_t)(t * 256 + k) * 8 + g]);
      for (int c = 0; c < NC; ++c)
        WT[(size_t)c * COPY_US + WGT_OFF_US + j] = v;
    }
  }
}

// ---------------------------------------------------------------------------
__global__ __launch_bounds__(256, 3)
void dmoe_main(const float* __restrict__ x,
               const unsigned short* __restrict__ WT,
               const float* __restrict__ b_share,
               const float* __restrict__ b_task,
               const float* __restrict__ b_gate,
               float* __restrict__ out, int NC) {
  __shared__ unsigned short Bs0[HUNIT_B / 2];   // 17408 B (64 h-rows)
  __shared__ unsigned short Bs1[HUNIT_B / 2];   // 17408 B
  __shared__ float gatesL[8 * 68];              // [gate-col][row(64)+pad]
  __shared__ float biasLds[8 * 64];             // slot-indexed, block h-range

  const int tid  = threadIdx.x;
  const int lane = tid & 63;
  const int w    = tid >> 6;    // wave 0..3
  const int col  = lane & 15;
  const int quad = lane >> 4;
  const int mg   = w >> 1;      // rows [mg*32, mg*32+32)
  const int ng   = w & 1;       // h    [ng*32, ng*32+32) within block h-half
  const int blk  = blockIdx.x;
  const int t    = blk & 1;     // task (== XCD parity: one task per XCD)
  const int hh   = (blk >> 1) & 1;   // h half of the units
  const int rt   = blk >> 2;    // row tile (64 rows)
  const int rot  = (blk >> 3) & 7;

  const char* WTc = (const char*)WT + (size_t)((blk >> 3) % NC) * COPY_B;

  // ---- reg staging of this wave's 4352-B chunk of one h-half-unit ----
  uint4 p0, p1, p2, p3; unsigned p4;
  auto stageIssue = [&](int un) {
    const char* g = WTc + (size_t)un * UNIT_B + hh * HUNIT_B + w * WAVE_B;
    p0 = *(const uint4*)(g + lane * 16);
    p1 = *(const uint4*)(g + 1024 + lane * 16);
    p2 = *(const uint4*)(g + 2048 + lane * 16);
    p3 = *(const uint4*)(g + 3072 + lane * 16);
    p4 = *(const unsigned*)(g + 4096 + lane * 4);
  };
  auto deposit = [&](unsigned short* dst) {
    char* l = (char*)dst + w * WAVE_B;
    *(uint4*)(l + lane * 16)        = p0;
    *(uint4*)(l + 1024 + lane * 16) = p1;
    *(uint4*)(l + 2048 + lane * 16) = p2;
    *(uint4*)(l + 3072 + lane * 16) = p3;
    *(unsigned*)(l + 4096 + lane * 4) = p4;
  };

  // ---- issue first unit's loads first (longest latency) ----
  const int e0 = slot2e(rot, t);
  stageIssue(e0 * 2);

  // ---- A-fragments: 2 m-tiles x 8 k-steps resident; pin into AGPRs ----
  short8 A[2][8];
  {
    const float* xb = x + ((size_t)rt * 64 + mg * 32 + col) * 256 + quad * 8;
    #pragma unroll
    for (int mt = 0; mt < 2; ++mt) {
      const float* xr = xb + (size_t)mt * 16 * 256;
      #pragma unroll
      for (int k = 0; k < 8; ++k) {
        float4v u = *(const float4v*)(xr + k * 32);
        float4v v = *(const float4v*)(xr + k * 32 + 4);
        short8 fr;
        fr[0] = (short)f2bf(u[0]); fr[1] = (short)f2bf(u[1]);
        fr[2] = (short)f2bf(u[2]); fr[3] = (short)f2bf(u[3]);
        fr[4] = (short)f2bf(v[0]); fr[5] = (short)f2bf(v[1]);
        fr[6] = (short)f2bf(v[2]); fr[7] = (short)f2bf(v[3]);
        A[mt][k] = fr;
        asm volatile("" : "+a"(A[mt][k]));   // force AGPR residency (R9-proven)
      }
    }
  }

  // ---- deposit first unit (frees p-regs before the gate phase) ----
  deposit(Bs0);

  // ---- biases -> LDS (slot-indexed; only this block's 64-h range) ----
  for (int i = tid; i < 512; i += 256) {
    int sr = i >> 6, hl = i & 63, h = hh * 64 + hl;
    biasLds[i] = (sr < 4) ? b_share[sr * 128 + h]
                          : b_task[(size_t)(t * 4 + (sr - 4)) * 128 + h];
  }

  // ---- gates: this task's 8 logit cols (cols 8..15 duplicate 0..7) ----
  {
    const unsigned short* WgT = (const unsigned short*)(WTc + WGT_OFF_US * 2);
    const int gr = col & 7;
    const unsigned short* bp = WgT + (size_t)(t * 8 + gr) * 256 + quad * 8;
    float bg = b_gate[t * 8 + gr];
    float4v ag[2] = {{0.f,0.f,0.f,0.f},{0.f,0.f,0.f,0.f}};
    #pragma unroll
    for (int kb = 0; kb < 2; ++kb) {           // 2 k-halves: caps reg peak
      short8 Bg[4];
      #pragma unroll
      for (int j = 0; j < 4; ++j) Bg[j] = *(const short8*)(bp + (kb * 4 + j) * 32);
      #pragma unroll
      for (int j = 0; j < 4; ++j) {
        ag[0] = __builtin_amdgcn_mfma_f32_16x16x32_bf16(A[0][kb * 4 + j], Bg[j], ag[0], 0, 0, 0);
        ag[1] = __builtin_amdgcn_mfma_f32_16x16x32_bf16(A[1][kb * 4 + j], Bg[j], ag[1], 0, 0, 0);
      }
    }
    #pragma unroll
    for (int mt = 0; mt < 2; ++mt) {
      #pragma unroll
      for (int r = 0; r < 4; ++r) {
        float vlog = ag[mt][r] + bg;
        float m = vlog;                      // softmax over 8 cols
        m = fmaxf(m, __shfl_xor(m, 1));
        m = fmaxf(m, __shfl_xor(m, 2));
        m = fmaxf(m, __shfl_xor(m, 4));
        float p = __expf(vlog - m);
        float s = p;
        s += __shfl_xor(s, 1);
        s += __shfl_xor(s, 2);
        s += __shfl_xor(s, 4);
        if (ng == 0 && col < 8)
          gatesL[col * 68 + mg * 32 + mt * 16 + quad * 4 + r] = p / s;
      }
    }
  }
  __syncthreads();

  // ---- accumulators (task-local) ----
  float tw[2][2][4];   // [mt][nt][r]
  #pragma unroll
  for (int mt = 0; mt < 2; ++mt)
    #pragma unroll
    for (int nt = 0; nt < 2; ++nt)
      #pragma unroll
      for (int r = 0; r < 4; ++r)
        tw[mt][nt][r] = 0.f;

  const int hb = ng * 32;
  float4v acc[2][2];

  // ---- slot loop: 8 experts x 2 k-halves; buffer parity = kh ----
  #pragma unroll 1
  for (int s = 0; s < 8; ++s) {
    const int sr  = (s + rot) & 7;
    const int e   = slot2e(sr, t);
    const int e2  = slot2e((s + 1 + rot) & 7, t);
    #pragma unroll
    for (int kh = 0; kh < 2; ++kh) {
      const bool doStage = !(s == 7 && kh == 1);
      if (doStage) stageIssue(kh == 0 ? e * 2 + 1 : e2 * 2);
      if (kh == 0) {
        #pragma unroll
        for (int mt = 0; mt < 2; ++mt)
          #pragma unroll
          for (int nt = 0; nt < 2; ++nt)
            acc[mt][nt] = (float4v){0.f, 0.f, 0.f, 0.f};
      }
      // compute this half-unit from Bs[kh]
      {
        const char* Bb = (const char*)(kh ? Bs1 : Bs0);
        __builtin_amdgcn_s_setprio(1);
        #pragma unroll
        for (int kk = 0; kk < 4; ++kk) {
          #pragma unroll
          for (int nt = 0; nt < 2; ++nt) {
            short8 bfr = *(const short8*)(Bb + (hb + nt * 16 + col) * ROW_B
                                          + kk * 64 + quad * 16);
            acc[0][nt] = __builtin_amdgcn_mfma_f32_16x16x32_bf16(
                A[0][kh * 4 + kk], bfr, acc[0][nt], 0, 0, 0);
            acc[1][nt] = __builtin_amdgcn_mfma_f32_16x16x32_bf16(
                A[1][kh * 4 + kk], bfr, acc[1][nt], 0, 0, 0);
          }
        }
        __builtin_amdgcn_s_setprio(0);
      }
      // deposit prefetched unit into the other buffer
      if (doStage) deposit(kh ? Bs0 : Bs1);
      // epilogue after second half
      if (kh == 1) {
        #pragma unroll
        for (int mt = 0; mt < 2; ++mt) {
          int rb = mg * 32 + mt * 16 + quad * 4;
          float4 g = *(const float4*)&gatesL[sr * 68 + rb];
          #pragma unroll
          for (int nt = 0; nt < 2; ++nt) {
            float bias = biasLds[sr * 64 + hb + nt * 16 + col];
            #pragma unroll
            for (int r = 0; r < 4; ++r) {
              float v = fmaxf(acc[mt][nt][r] + bias, 0.f);
              tw[mt][nt][r] += ((const float*)&g)[r] * v;
            }
          }
        }
      }
      __syncthreads();
    }
  }

  // ---- write towers (nontemporal): out[t][row][h] ----
  #pragma unroll
  for (int mt = 0; mt < 2; ++mt)
    #pragma unroll
    for (int r = 0; r < 4; ++r) {
      size_t row = (size_t)rt * 64 + mg * 32 + mt * 16 + quad * 4 + r;
      float* op = out + ((size_t)t << 22) + row * 128 + hh * 64 + hb;
      #pragma unroll
      for (int nt = 0; nt < 2; ++nt)
        __builtin_nontemporal_store(tw[mt][nt][r], op + nt * 16 + col);
    }
}

// ---------------------------------------------------------------------------
extern "C" void kernel_launch(void* const* d_in, const int* in_sizes, int n_in,
                              void* d_out, int out_size, void* d_ws, size_t ws_size,
                              hipStream_t stream) {
  const float* x       = (const float*)d_in[0];
  const float* W_share = (const float*)d_in[1];
  const float* b_share = (const float*)d_in[2];
  const float* W_task  = (const float*)d_in[3];
  const float* b_task  = (const float*)d_in[4];
  const float* W_gate  = (const float*)d_in[5];
  const float* b_gate  = (const float*)d_in[6];
  float* out = (float*)d_out;
  unsigned short* WT = (unsigned short*)d_ws;

  int NC = (int)(ws_size / (size_t)COPY_B);
  if (NC < 1) NC = 1;
  if (NC > 2) NC = 2;

  prep_kernel<<<97, 256, 0, stream>>>(W_share, W_task, W_gate, WT, NC);
  dmoe_main<<<2048, 256, 0, stream>>>(x, WT, b_share, b_task, b_gate, out, NC);
}